// Round 2
// baseline (1532.470 us; speedup 1.0000x reference)
//
#include <hip/hip_runtime.h>
#include <math.h>

// Problem constants
#define B_   8
#define S_   512
#define D_   768
#define H_   12
#define DH_  64
#define NTOK (B_*S_)   // 4096
#define D2_  (2*D_)    // 1536

// ---------- batched GEMM+bias: Y[z] = X[z] @ W[z] + b[z] ----------
// X: [M,K] (row stride ldx), W: [K,N] (row stride N), Y: [M,N] (row stride ldy)
// Tile: 64x64, BK=16, 256 threads, 4x4 per thread, fp32 accumulate.
struct GemmBatch {
    const float* X[6];
    const float* W[6];
    const float* bias[6];
    float*       Y[6];
};

#define BM 64
#define BN 64
#define BK 16
#define LDT 68   // padded LDS row stride

__global__ __launch_bounds__(256) void gemm_bias(
    GemmBatch gb, int M, int N, int K, int ldx, int ldy)
{
    __shared__ float As[BK * LDT];
    __shared__ float Bs[BK * LDT];

    const int z = blockIdx.z;
    const float* __restrict__ X    = gb.X[z];
    const float* __restrict__ W    = gb.W[z];
    const float* __restrict__ bias = gb.bias[z];
    float* __restrict__ Y          = gb.Y[z];

    const int tid = threadIdx.x;
    const int bn = blockIdx.x * BN;
    const int bm = blockIdx.y * BM;
    const int tx = tid & 15, ty = tid >> 4;
    const int m0 = ty * 4, n0 = tx * 4;

    float acc[4][4] = {};

    // load-index decomposition
    const int arow = tid >> 2;   // 0..63  (row within A tile)
    const int ac4  = tid & 3;    // 0..3   (float4 group along K)
    const int bkk  = tid >> 4;   // 0..15  (k within B tile)
    const int bc4  = tid & 15;   // 0..15  (float4 group along N)

    for (int k0 = 0; k0 < K; k0 += BK) {
        // A tile 64x16, store transposed As[kk][m]
        {
            const float* p = X + (size_t)(bm + arow) * ldx + k0 + ac4 * 4;
            float4 u = *(const float4*)p;
            As[(ac4 * 4 + 0) * LDT + arow] = u.x;
            As[(ac4 * 4 + 1) * LDT + arow] = u.y;
            As[(ac4 * 4 + 2) * LDT + arow] = u.z;
            As[(ac4 * 4 + 3) * LDT + arow] = u.w;
        }
        // B tile 16x64, natural Bs[kk][n]
        {
            const float* p = W + (size_t)(k0 + bkk) * N + bn + bc4 * 4;
            float4 u = *(const float4*)p;
            *(float4*)&Bs[bkk * LDT + bc4 * 4] = u;
        }
        __syncthreads();

        #pragma unroll
        for (int kk = 0; kk < BK; ++kk) {
            float4 a = *(const float4*)&As[kk * LDT + m0];
            float4 b = *(const float4*)&Bs[kk * LDT + n0];
            float av[4] = {a.x, a.y, a.z, a.w};
            float bv[4] = {b.x, b.y, b.z, b.w};
            #pragma unroll
            for (int i = 0; i < 4; ++i)
                #pragma unroll
                for (int j = 0; j < 4; ++j)
                    acc[i][j] += av[i] * bv[j];
        }
        __syncthreads();
    }

    float4 bv = *(const float4*)&bias[bn + n0];
    float bvv[4] = {bv.x, bv.y, bv.z, bv.w};

    #pragma unroll
    for (int i = 0; i < 4; ++i) {
        float* yp = Y + (size_t)(bm + m0 + i) * ldy + bn + n0;
        float4 o;
        o.x = acc[i][0] + bvv[0];
        o.y = acc[i][1] + bvv[1];
        o.z = acc[i][2] + bvv[2];
        o.w = acc[i][3] + bvv[3];
        *(float4*)yp = o;
    }
}

// ---------- fused online-softmax attention ----------
// One thread = one query row. Block = 128 threads (128 queries), grid:
// (S/128, B*H, 4 attention variants). K/V tiles of 32 keys staged in LDS
// (broadcast reads -> conflict-free). fp32 throughout.
#define QT 128
#define KT 32

__global__ __launch_bounds__(128) void attn_kernel(
    const float* __restrict__ q,  const float* __restrict__ k,
    const float* __restrict__ v,  const float* __restrict__ qm,
    const float* __restrict__ km, const float* __restrict__ vm,
    float* __restrict__ catP, float* __restrict__ catM)
{
    __shared__ float smem[QT * 65];  // phase1: q staging [128][65]; phase2: K[0..2047] V[2048..4095]

    const float* Q;
    const float* Kp;
    const float* Vp;
    float* Out;
    int col0;
    switch (blockIdx.z) {
        case 0:  Q = q;  Kp = k;  Vp = v;  Out = catP; col0 = 0;   break;  // a_pp
        case 1:  Q = qm; Kp = k;  Vp = v;  Out = catP; col0 = D_;  break;  // a_mp
        case 2:  Q = qm; Kp = km; Vp = vm; Out = catM; col0 = 0;   break;  // a_mm
        default: Q = q;  Kp = km; Vp = vm; Out = catM; col0 = D_;  break;  // a_pm
    }

    const int tid = threadIdx.x;
    const int bh = blockIdx.y;
    const int b = bh / H_, h = bh % H_;
    const int q0 = blockIdx.x * QT;
    const size_t base = (size_t)b * S_ * D_ + h * DH_;  // (b, s=0, h, d=0)

    // ---- phase 1: stage Q tile (coalesced), copy own row to registers ----
    for (int u = tid; u < QT * (DH_ / 4); u += QT) {   // 2048 float4 units
        int row = u >> 4, c4 = u & 15;
        float4 uu = *(const float4*)(Q + base + (size_t)(q0 + row) * D_ + c4 * 4);
        float* s = &smem[row * 65 + c4 * 4];
        s[0] = uu.x; s[1] = uu.y; s[2] = uu.z; s[3] = uu.w;
    }
    __syncthreads();
    float qreg[DH_];
    #pragma unroll
    for (int d = 0; d < DH_; ++d) qreg[d] = smem[tid * 65 + d];
    __syncthreads();

    float o[DH_];
    #pragma unroll
    for (int d = 0; d < DH_; ++d) o[d] = 0.f;
    float mrun = -INFINITY, lrun = 0.f;
    const float scale = 0.125f;  // 1/sqrt(64)

    for (int kt = 0; kt < S_; kt += KT) {
        // stage K,V tiles (32x64 each)
        for (int u = tid; u < KT * (DH_ / 4); u += QT) {  // 512 units, 4/thread
            int row = u >> 4, c4 = u & 15;
            size_t g = base + (size_t)(kt + row) * D_ + c4 * 4;
            float4 ku = *(const float4*)(Kp + g);
            float4 vu = *(const float4*)(Vp + g);
            int o4 = row * DH_ + c4 * 4;
            smem[o4 + 0] = ku.x; smem[o4 + 1] = ku.y;
            smem[o4 + 2] = ku.z; smem[o4 + 3] = ku.w;
            smem[2048 + o4 + 0] = vu.x; smem[2048 + o4 + 1] = vu.y;
            smem[2048 + o4 + 2] = vu.z; smem[2048 + o4 + 3] = vu.w;
        }
        __syncthreads();

        float s[KT];
        float mt = mrun;
        #pragma unroll
        for (int j = 0; j < KT; ++j) {
            float acc = 0.f;
            #pragma unroll
            for (int d = 0; d < DH_; ++d) acc += qreg[d] * smem[j * DH_ + d];
            s[j] = acc * scale;
            mt = fmaxf(mt, s[j]);
        }
        float alpha = __expf(mrun - mt);   // first tile: exp(-inf)=0
        lrun *= alpha;
        #pragma unroll
        for (int d = 0; d < DH_; ++d) o[d] *= alpha;
        #pragma unroll
        for (int j = 0; j < KT; ++j) {
            float p = __expf(s[j] - mt);
            lrun += p;
            #pragma unroll
            for (int d = 0; d < DH_; ++d) o[d] += p * smem[2048 + j * DH_ + d];
        }
        mrun = mt;
        __syncthreads();
    }

    const float inv = 1.f / lrun;
    float* yp = Out + (size_t)(b * S_ + q0 + tid) * D2_ + col0 + h * DH_;
    #pragma unroll
    for (int d = 0; d < DH_; d += 4) {
        float4 o4;
        o4.x = o[d] * inv; o4.y = o[d + 1] * inv;
        o4.z = o[d + 2] * inv; o4.w = o[d + 3] * inv;
        *(float4*)(yp + d) = o4;
    }
}

// ---------- launch ----------
extern "C" void kernel_launch(void* const* d_in, const int* in_sizes, int n_in,
                              void* d_out, int out_size, void* d_ws, size_t ws_size,
                              hipStream_t stream) {
    const float* hs   = (const float*)d_in[0];
    const float* mol  = (const float*)d_in[1];
    const float* Wq   = (const float*)d_in[2];
    const float* bq   = (const float*)d_in[3];
    const float* Wk   = (const float*)d_in[4];
    const float* bk   = (const float*)d_in[5];
    const float* Wv   = (const float*)d_in[6];
    const float* bv   = (const float*)d_in[7];
    const float* Wqm  = (const float*)d_in[8];
    const float* bqm  = (const float*)d_in[9];
    const float* Wkm  = (const float*)d_in[10];
    const float* bkm  = (const float*)d_in[11];
    const float* Wvm  = (const float*)d_in[12];
    const float* bvm  = (const float*)d_in[13];
    const float* Wfc  = (const float*)d_in[14];
    const float* bfc  = (const float*)d_in[15];
    const float* Wfcm = (const float*)d_in[16];
    const float* bfcm = (const float*)d_in[17];
    const float* Wo   = (const float*)d_in[18];
    const float* bo   = (const float*)d_in[19];
    const float* Wom  = (const float*)d_in[20];
    const float* bom  = (const float*)d_in[21];

    float* out = (float*)d_out;
    float* ws  = (float*)d_ws;

    const size_t ND = (size_t)NTOK * D_;   // 3,145,728
    float* q    = ws + 0 * ND;
    float* k    = ws + 1 * ND;
    float* v    = ws + 2 * ND;
    float* qm   = ws + 3 * ND;
    float* km   = ws + 4 * ND;
    float* vm   = ws + 5 * ND;
    float* catP = ws + 6 * ND;    // [NTOK, 1536]
    float* catM = ws + 8 * ND;    // [NTOK, 1536]
    // fc outputs reuse q/k space (dead after attention)
    float* fcP  = ws + 0 * ND;    // [NTOK, 768]
    float* fcM  = ws + 1 * ND;    // [NTOK, 768]

    dim3 blk(256);

    // 1) six QKV projections in one batched launch
    {
        GemmBatch gb;
        gb.X[0] = hs;  gb.W[0] = Wq;  gb.bias[0] = bq;  gb.Y[0] = q;
        gb.X[1] = hs;  gb.W[1] = Wk;  gb.bias[1] = bk;  gb.Y[1] = k;
        gb.X[2] = hs;  gb.W[2] = Wv;  gb.bias[2] = bv;  gb.Y[2] = v;
        gb.X[3] = mol; gb.W[3] = Wqm; gb.bias[3] = bqm; gb.Y[3] = qm;
        gb.X[4] = mol; gb.W[4] = Wkm; gb.bias[4] = bkm; gb.Y[4] = km;
        gb.X[5] = mol; gb.W[5] = Wvm; gb.bias[5] = bvm; gb.Y[5] = vm;
        dim3 g6(D_ / BN, NTOK / BM, 6);
        gemm_bias<<<g6, blk, 0, stream>>>(gb, NTOK, D_, D_, D_, D_);
    }

    // 2) four attentions, one launch
    {
        dim3 ablk(QT);
        dim3 agrid(S_ / QT, B_ * H_, 4);
        attn_kernel<<<agrid, ablk, 0, stream>>>(q, k, v, qm, km, vm, catP, catM);
    }

    // 3) two concat-FC GEMMs (K = 1536)
    {
        GemmBatch gb = {};
        gb.X[0] = catP; gb.W[0] = Wfc;  gb.bias[0] = bfc;  gb.Y[0] = fcP;
        gb.X[1] = catM; gb.W[1] = Wfcm; gb.bias[1] = bfcm; gb.Y[1] = fcM;
        dim3 g2(D_ / BN, NTOK / BM, 2);
        gemm_bias<<<g2, blk, 0, stream>>>(gb, NTOK, D_, D2_, D2_, D_);
    }

    // 4) two output projections -> d_out
    {
        GemmBatch gb = {};
        gb.X[0] = fcP; gb.W[0] = Wo;  gb.bias[0] = bo;  gb.Y[0] = out;
        gb.X[1] = fcM; gb.W[1] = Wom; gb.bias[1] = bom; gb.Y[1] = out + ND;
        dim3 g2(D_ / BN, NTOK / BM, 2);
        gemm_bias<<<g2, blk, 0, stream>>>(gb, NTOK, D_, D_, D_, D_);
    }
}

// Round 3
// 364.374 us; speedup vs baseline: 4.2058x; 4.2058x over previous
//
#include <hip/hip_runtime.h>
#include <math.h>

#define B_   8
#define S_   512
#define D_   768
#define H_   12
#define DH_  64
#define NTOK (B_*S_)        // 4096
#define D2_  (2*D_)         // 1536
#define ND_  ((size_t)NTOK * D_)      // 3145728
#define WSZ_ ((size_t)D_ * D_)        // 589824
#define FSZ_ ((size_t)D2_ * D_)       // 1179648

typedef unsigned short ushortT;
typedef short bf16x8 __attribute__((ext_vector_type(8)));
typedef float f32x4  __attribute__((ext_vector_type(4)));
typedef unsigned int u32;

__device__ __forceinline__ unsigned short f2bf(float f) {
    unsigned int x = __float_as_uint(f);
    unsigned int lsb = (x >> 16) & 1u;
    x += 0x7fffu + lsb;            // round-to-nearest-even
    return (unsigned short)(x >> 16);
}

// async global(16B)->LDS, per-lane addresses; LDS dest must be uniform-base + lane*16
__device__ __forceinline__ void ld_g2l16(const ushortT* g, ushortT* l) {
    __builtin_amdgcn_global_load_lds(
        (const __attribute__((address_space(1))) u32*)g,
        (__attribute__((address_space(3))) u32*)l, 16, 0, 0);
}

// ---------------- fp32 -> bf16 elementwise (hs, mol) ----------------
__global__ __launch_bounds__(256) void convert_bf16_k(
    const float* __restrict__ a, const float* __restrict__ b,
    ushortT* __restrict__ oa, ushortT* __restrict__ ob)
{
    const float* in = blockIdx.z ? b : a;
    ushortT* out = blockIdx.z ? ob : oa;
    size_t i = ((size_t)blockIdx.x * 256 + threadIdx.x) * 4;
    float4 f = *(const float4*)(in + i);
    ushort4 u;
    u.x = f2bf(f.x); u.y = f2bf(f.y); u.z = f2bf(f.z); u.w = f2bf(f.w);
    *(ushort4*)(out + i) = u;
}

// ---------------- weight transpose+convert: in[R][768] fp32 -> out[768][R] bf16 ----------------
struct TransJob {
    const float* in[10];
    ushortT*     out[10];
    int          R[10];
};
__global__ __launch_bounds__(256) void transpose_w(TransJob tj)
{
    __shared__ float t[32][33];
    const int z = blockIdx.z;
    const int R = tj.R[z];
    const int r0 = blockIdx.y * 32;
    if (r0 >= R) return;                      // block-uniform
    const float* __restrict__ in = tj.in[z];
    ushortT* __restrict__ out = tj.out[z];
    const int c0 = blockIdx.x * 32;
    const int x = threadIdx.x & 31, y = threadIdx.x >> 5;   // y: 0..7
    #pragma unroll
    for (int i = 0; i < 4; ++i)
        t[y + 8 * i][x] = in[(size_t)(r0 + y + 8 * i) * D_ + c0 + x];
    __syncthreads();
    #pragma unroll
    for (int i = 0; i < 4; ++i)
        out[(size_t)(c0 + y + 8 * i) * R + r0 + x] = f2bf(t[x][y + 8 * i]);
}

// ---------------- V transpose: [4096][768] bf16 -> [96][64][512] bf16 ----------------
__global__ __launch_bounds__(256) void transpose_v(
    const ushortT* __restrict__ v, const ushortT* __restrict__ vm,
    ushortT* __restrict__ vt, ushortT* __restrict__ vmt)
{
    __shared__ ushortT t[64][65];
    const ushortT* __restrict__ in = blockIdx.z ? vm : v;
    ushortT* __restrict__ out = blockIdx.z ? vmt : vt;
    const int bh = blockIdx.y, b = bh / H_, h = bh % H_;
    const int s0 = blockIdx.x * 64;
    const int c4 = threadIdx.x & 15, r = threadIdx.x >> 4;   // r: 0..15
    #pragma unroll
    for (int i = 0; i < 4; ++i) {
        int row = r + 16 * i;                                 // s within tile
        ushort4 u = *(const ushort4*)(in + (size_t)(b * S_ + s0 + row) * D_ + h * DH_ + c4 * 4);
        t[row][c4 * 4 + 0] = u.x; t[row][c4 * 4 + 1] = u.y;
        t[row][c4 * 4 + 2] = u.z; t[row][c4 * 4 + 3] = u.w;
    }
    __syncthreads();
    #pragma unroll
    for (int i = 0; i < 4; ++i) {
        int d = r + 16 * i;
        ushort4 u;
        u.x = t[c4 * 4 + 0][d]; u.y = t[c4 * 4 + 1][d];
        u.z = t[c4 * 4 + 2][d]; u.w = t[c4 * 4 + 3][d];
        *(ushort4*)(out + (size_t)(bh * DH_ + d) * S_ + s0 + c4 * 4) = u;
    }
}

// ---------------- MFMA GEMM: Y[z] = X[z] @ Wt[z]^T + bias[z] ----------------
// X: [4096][K] bf16, Wt: [768][K] bf16 (pre-transposed), Y: [4096][768]
// 128x128 tile, BK=32, 256 thr = 4 waves (2x2), each wave 4x4 of 16x16x32 MFMA.
struct GemmJob {
    const ushortT* X[6];
    const ushortT* Wt[6];
    const float*   bias[6];
    void*          Y[6];
};
__global__ __launch_bounds__(256) void gemm_mfma(GemmJob gb, int K, int out_f32)
{
    __shared__ __attribute__((aligned(16))) ushortT At[128 * 32];
    __shared__ __attribute__((aligned(16))) ushortT Bt[128 * 32];

    const int z = blockIdx.z;
    const ushortT* __restrict__ X  = gb.X[z];
    const ushortT* __restrict__ Wt = gb.Wt[z];
    const float* __restrict__ bias = gb.bias[z];

    const int tid = threadIdx.x;
    const int lane = tid & 63, wave = tid >> 6;
    const int quad = lane >> 4, l16 = lane & 15;
    const int wm = wave >> 1, wn = wave & 1;
    const int bm = blockIdx.y * 128, bn = blockIdx.x * 128;

    f32x4 acc[4][4];
    #pragma unroll
    for (int i = 0; i < 4; ++i)
        #pragma unroll
        for (int j = 0; j < 4; ++j)
            acc[i][j] = (f32x4){0.f, 0.f, 0.f, 0.f};

    const int c0 = tid, c1 = tid + 256;
    const int r0c = c0 >> 2, k0c = (c0 & 3) * 8;
    const int r1c = c1 >> 2, k1c = (c1 & 3) * 8;

    for (int k0 = 0; k0 < K; k0 += 32) {
        __syncthreads();
        ld_g2l16(X  + (size_t)(bm + r0c) * K + k0 + k0c, &At[c0 * 8]);
        ld_g2l16(X  + (size_t)(bm + r1c) * K + k0 + k1c, &At[c1 * 8]);
        ld_g2l16(Wt + (size_t)(bn + r0c) * K + k0 + k0c, &Bt[c0 * 8]);
        ld_g2l16(Wt + (size_t)(bn + r1c) * K + k0 + k1c, &Bt[c1 * 8]);
        __syncthreads();

        bf16x8 af[4], bf[4];
        #pragma unroll
        for (int mt = 0; mt < 4; ++mt)
            af[mt] = *(const bf16x8*)&At[(wm * 64 + mt * 16 + l16) * 32 + quad * 8];
        #pragma unroll
        for (int nt = 0; nt < 4; ++nt)
            bf[nt] = *(const bf16x8*)&Bt[(wn * 64 + nt * 16 + l16) * 32 + quad * 8];
        #pragma unroll
        for (int mt = 0; mt < 4; ++mt)
            #pragma unroll
            for (int nt = 0; nt < 4; ++nt)
                acc[mt][nt] = __builtin_amdgcn_mfma_f32_16x16x32_bf16(af[mt], bf[nt], acc[mt][nt], 0, 0, 0);
    }

    const int row0 = bm + wm * 64, col0 = bn + wn * 64;
    #pragma unroll
    for (int mt = 0; mt < 4; ++mt) {
        #pragma unroll
        for (int nt = 0; nt < 4; ++nt) {
            const int col = col0 + nt * 16 + l16;
            const float bval = bias[col];
            #pragma unroll
            for (int r = 0; r < 4; ++r) {
                const int row = row0 + mt * 16 + quad * 4 + r;
                float vsum = acc[mt][nt][r] + bval;
                if (out_f32) ((float*)gb.Y[z])[(size_t)row * D_ + col] = vsum;
                else         ((ushortT*)gb.Y[z])[(size_t)row * D_ + col] = f2bf(vsum);
            }
        }
    }
}

// ---------------- MFMA flash attention ----------------
// Block: 256 thr = 4 waves, each wave 32 Q-rows (block: 128 Q-rows).
// Grid: (S/128, B*H, 4 variants). K-tile/Vt-tile = 64 keys in LDS via DMA.
__global__ __launch_bounds__(256) void attn_mfma(
    const ushortT* __restrict__ q,  const ushortT* __restrict__ k,
    const ushortT* __restrict__ vt, const ushortT* __restrict__ qm,
    const ushortT* __restrict__ km, const ushortT* __restrict__ vmt,
    ushortT* __restrict__ catP, ushortT* __restrict__ catM)
{
    __shared__ __attribute__((aligned(16))) ushortT Kt[64 * 64];
    __shared__ __attribute__((aligned(16))) ushortT Vt[64 * 64];
    __shared__ __attribute__((aligned(16))) ushortT Pt[4][32 * 72];   // pad 72

    const int tid = threadIdx.x;
    const int lane = tid & 63, wave = tid >> 6;
    const int quad = lane >> 4, l16 = lane & 15;
    const int bh = blockIdx.y, b = bh / H_, h = bh % H_;
    const int q0 = blockIdx.x * 128 + wave * 32;

    const ushortT *Q, *Kp, *Vp;
    ushortT* Out;
    int colbase;
    switch (blockIdx.z) {
        case 0:  Q = q;  Kp = k;  Vp = vt;  Out = catP; colbase = 0;  break;  // a_pp
        case 1:  Q = qm; Kp = k;  Vp = vt;  Out = catP; colbase = D_; break;  // a_mp
        case 2:  Q = qm; Kp = km; Vp = vmt; Out = catM; colbase = 0;  break;  // a_mm
        default: Q = q;  Kp = km; Vp = vmt; Out = catM; colbase = D_; break;  // a_pm
    }

    // Q fragments: A-layout, lane reads Q[m=l16][k-chunk], kept in regs all loop.
    bf16x8 Qf[2][2];
    #pragma unroll
    for (int mt = 0; mt < 2; ++mt)
        #pragma unroll
        for (int kc = 0; kc < 2; ++kc)
            Qf[mt][kc] = *(const bf16x8*)(Q + (size_t)(b * S_ + q0 + mt * 16 + l16) * D_
                                            + h * DH_ + kc * 32 + quad * 8);

    f32x4 O[2][4];
    #pragma unroll
    for (int mt = 0; mt < 2; ++mt)
        #pragma unroll
        for (int dt = 0; dt < 4; ++dt)
            O[mt][dt] = (f32x4){0.f, 0.f, 0.f, 0.f};
    float mrun[2][4], lrun[2][4];
    #pragma unroll
    for (int mt = 0; mt < 2; ++mt)
        #pragma unroll
        for (int r = 0; r < 4; ++r) { mrun[mt][r] = -INFINITY; lrun[mt][r] = 0.f; }

    const ushortT* Kbase = Kp + (size_t)(b * S_) * D_ + h * DH_;
    const ushortT* Vbase = Vp + (size_t)bh * DH_ * S_;
    const float scale = 0.125f;   // 1/sqrt(64)

    for (int kt = 0; kt < S_; kt += 64) {
        __syncthreads();   // prior tile's reads complete
        #pragma unroll
        for (int rr = 0; rr < 2; ++rr) {
            int c = tid + rr * 256;
            int key = c >> 3, dc = (c & 7) * 8;        // K-tile [key][d]
            ld_g2l16(Kbase + (size_t)(kt + key) * D_ + dc, &Kt[c * 8]);
            ld_g2l16(Vbase + (size_t)key * S_ + kt + dc, &Vt[c * 8]);  // Vt-tile [d][s]
        }
        __syncthreads();   // staging drained (syncthreads waits vmcnt(0))

        // ---- S = Q K^T ----
        f32x4 S[2][4];
        #pragma unroll
        for (int mt = 0; mt < 2; ++mt)
            #pragma unroll
            for (int nt = 0; nt < 4; ++nt)
                S[mt][nt] = (f32x4){0.f, 0.f, 0.f, 0.f};
        #pragma unroll
        for (int nt = 0; nt < 4; ++nt) {
            bf16x8 bk0 = *(const bf16x8*)&Kt[(nt * 16 + l16) * 64 + quad * 8];
            bf16x8 bk1 = *(const bf16x8*)&Kt[(nt * 16 + l16) * 64 + 32 + quad * 8];
            #pragma unroll
            for (int mt = 0; mt < 2; ++mt) {
                S[mt][nt] = __builtin_amdgcn_mfma_f32_16x16x32_bf16(Qf[mt][0], bk0, S[mt][nt], 0, 0, 0);
                S[mt][nt] = __builtin_amdgcn_mfma_f32_16x16x32_bf16(Qf[mt][1], bk1, S[mt][nt], 0, 0, 0);
            }
        }

        // ---- online softmax (rows = quad*4+r, cols spread over l16 x nt) ----
        #pragma unroll
        for (int mt = 0; mt < 2; ++mt) {
            float rmax[4];
            #pragma unroll
            for (int r = 0; r < 4; ++r) {
                float mx = S[mt][0][r];
                #pragma unroll
                for (int nt = 1; nt < 4; ++nt) mx = fmaxf(mx, S[mt][nt][r]);
                rmax[r] = mx;
            }
            #pragma unroll
            for (int mask = 1; mask <= 8; mask <<= 1)
                #pragma unroll
                for (int r = 0; r < 4; ++r)
                    rmax[r] = fmaxf(rmax[r], __shfl_xor(rmax[r], mask, 64));

            float alpha[4];
            #pragma unroll
            for (int r = 0; r < 4; ++r) {
                float mnew = fmaxf(mrun[mt][r], rmax[r] * scale);
                alpha[r] = __expf(mrun[mt][r] - mnew);
                mrun[mt][r] = mnew;
                lrun[mt][r] *= alpha[r];
            }
            #pragma unroll
            for (int dt = 0; dt < 4; ++dt)
                #pragma unroll
                for (int r = 0; r < 4; ++r)
                    O[mt][dt][r] *= alpha[r];

            float rsum[4] = {0.f, 0.f, 0.f, 0.f};
            #pragma unroll
            for (int nt = 0; nt < 4; ++nt)
                #pragma unroll
                for (int r = 0; r < 4; ++r) {
                    float p = __expf(S[mt][nt][r] * scale - mrun[mt][r]);
                    S[mt][nt][r] = p;
                    rsum[r] += p;
                }
            #pragma unroll
            for (int mask = 1; mask <= 8; mask <<= 1)
                #pragma unroll
                for (int r = 0; r < 4; ++r)
                    rsum[r] += __shfl_xor(rsum[r], mask, 64);
            #pragma unroll
            for (int r = 0; r < 4; ++r) lrun[mt][r] += rsum[r];

            // P: C-layout -> LDS in A-read layout [m][key]
            #pragma unroll
            for (int nt = 0; nt < 4; ++nt)
                #pragma unroll
                for (int r = 0; r < 4; ++r)
                    Pt[wave][(mt * 16 + quad * 4 + r) * 72 + nt * 16 + l16] = f2bf(S[mt][nt][r]);
        }
        __syncthreads();   // P visible across lanes

        // ---- O += P V ----
        bf16x8 Pa[2][2];
        #pragma unroll
        for (int mt = 0; mt < 2; ++mt)
            #pragma unroll
            for (int kc = 0; kc < 2; ++kc)
                Pa[mt][kc] = *(const bf16x8*)&Pt[wave][(mt * 16 + l16) * 72 + kc * 32 + quad * 8];
        #pragma unroll
        for (int dt = 0; dt < 4; ++dt) {
            bf16x8 bv0 = *(const bf16x8*)&Vt[(dt * 16 + l16) * 64 + quad * 8];
            bf16x8 bv1 = *(const bf16x8*)&Vt[(dt * 16 + l16) * 64 + 32 + quad * 8];
            #pragma unroll
            for (int mt = 0; mt < 2; ++mt) {
                O[mt][dt] = __builtin_amdgcn_mfma_f32_16x16x32_bf16(Pa[mt][0], bv0, O[mt][dt], 0, 0, 0);
                O[mt][dt] = __builtin_amdgcn_mfma_f32_16x16x32_bf16(Pa[mt][1], bv1, O[mt][dt], 0, 0, 0);
            }
        }
    }

    // ---- epilogue ----
    #pragma unroll
    for (int mt = 0; mt < 2; ++mt)
        #pragma unroll
        for (int dt = 0; dt < 4; ++dt)
            #pragma unroll
            for (int r = 0; r < 4; ++r) {
                int row = q0 + mt * 16 + quad * 4 + r;
                int col = colbase + h * DH_ + dt * 16 + l16;
                float val = O[mt][dt][r] / lrun[mt][r];
                Out[(size_t)(b * S_ + row) * D2_ + col] = f2bf(val);
            }
}

// ---------------- launch ----------------
extern "C" void kernel_launch(void* const* d_in, const int* in_sizes, int n_in,
                              void* d_out, int out_size, void* d_ws, size_t ws_size,
                              hipStream_t stream) {
    const float* hs   = (const float*)d_in[0];
    const float* mol  = (const float*)d_in[1];
    const float* Wq   = (const float*)d_in[2];
    const float* bq   = (const float*)d_in[3];
    const float* Wk   = (const float*)d_in[4];
    const float* bk   = (const float*)d_in[5];
    const float* Wv   = (const float*)d_in[6];
    const float* bv   = (const float*)d_in[7];
    const float* Wqm  = (const float*)d_in[8];
    const float* bqm  = (const float*)d_in[9];
    const float* Wkm  = (const float*)d_in[10];
    const float* bkm  = (const float*)d_in[11];
    const float* Wvm  = (const float*)d_in[12];
    const float* bvm  = (const float*)d_in[13];
    const float* Wfc  = (const float*)d_in[14];
    const float* bfc  = (const float*)d_in[15];
    const float* Wfcm = (const float*)d_in[16];
    const float* bfcm = (const float*)d_in[17];
    const float* Wo   = (const float*)d_in[18];
    const float* bo   = (const float*)d_in[19];
    const float* Wom  = (const float*)d_in[20];
    const float* bom  = (const float*)d_in[21];

    float* out = (float*)d_out;
    ushortT* ws = (ushortT*)d_ws;

    ushortT* hsb  = ws;
    ushortT* molb = hsb + ND_;
    ushortT* WqT  = molb + ND_;
    ushortT* WkT  = WqT + WSZ_;
    ushortT* WvT  = WkT + WSZ_;
    ushortT* WqmT = WvT + WSZ_;
    ushortT* WkmT = WqmT + WSZ_;
    ushortT* WvmT = WkmT + WSZ_;
    ushortT* WfcT = WvmT + WSZ_;
    ushortT* WfcmT= WfcT + FSZ_;
    ushortT* WoT  = WfcmT + FSZ_;
    ushortT* WomT = WoT + WSZ_;
    ushortT* q    = WomT + WSZ_;
    ushortT* k    = q + ND_;
    ushortT* v    = k + ND_;
    ushortT* qm   = v + ND_;
    ushortT* km   = qm + ND_;
    ushortT* vm   = km + ND_;
    ushortT* vtr  = vm + ND_;
    ushortT* vmtr = vtr + ND_;
    ushortT* catP = vmtr + ND_;      // [4096][1536]
    ushortT* catM = catP + 2 * ND_;
    ushortT* fcP  = catM + 2 * ND_;
    ushortT* fcM  = fcP + ND_;

    // 1) fp32 -> bf16 for activations
    convert_bf16_k<<<dim3(ND_ / 1024, 1, 2), 256, 0, stream>>>(hs, mol, hsb, molb);

    // 2) transpose+convert the 10 weight matrices
    {
        TransJob tj;
        const float* wi[10] = {Wq, Wk, Wv, Wqm, Wkm, Wvm, Wfc, Wfcm, Wo, Wom};
        ushortT* wo_[10]    = {WqT, WkT, WvT, WqmT, WkmT, WvmT, WfcT, WfcmT, WoT, WomT};
        int      wr[10]     = {D_, D_, D_, D_, D_, D_, D2_, D2_, D_, D_};
        for (int i = 0; i < 10; ++i) { tj.in[i] = wi[i]; tj.out[i] = wo_[i]; tj.R[i] = wr[i]; }
        transpose_w<<<dim3(D_ / 32, D2_ / 32, 10), 256, 0, stream>>>(tj);
    }

    // 3) six QKV projections
    {
        GemmJob gb = {};
        gb.X[0] = hsb;  gb.Wt[0] = WqT;  gb.bias[0] = bq;  gb.Y[0] = q;
        gb.X[1] = hsb;  gb.Wt[1] = WkT;  gb.bias[1] = bk;  gb.Y[1] = k;
        gb.X[2] = hsb;  gb.Wt[2] = WvT;  gb.bias[2] = bv;  gb.Y[2] = v;
        gb.X[3] = molb; gb.Wt[3] = WqmT; gb.bias[3] = bqm; gb.Y[3] = qm;
        gb.X[4] = molb; gb.Wt[4] = WkmT; gb.bias[4] = bkm; gb.Y[4] = km;
        gb.X[5] = molb; gb.Wt[5] = WvmT; gb.bias[5] = bvm; gb.Y[5] = vm;
        gemm_mfma<<<dim3(D_ / 128, NTOK / 128, 6), 256, 0, stream>>>(gb, D_, 0);
    }

    // 4) V transpose to [B,H,DH,S]
    transpose_v<<<dim3(S_ / 64, B_ * H_, 2), 256, 0, stream>>>(v, vm, vtr, vmtr);

    // 5) four flash attentions -> concat buffers
    attn_mfma<<<dim3(S_ / 128, B_ * H_, 4), 256, 0, stream>>>(q, k, vtr, qm, km, vmtr, catP, catM);

    // 6) concat-FC GEMMs (K=1536)
    {
        GemmJob gb = {};
        gb.X[0] = catP; gb.Wt[0] = WfcT;  gb.bias[0] = bfc;  gb.Y[0] = fcP;
        gb.X[1] = catM; gb.Wt[1] = WfcmT; gb.bias[1] = bfcm; gb.Y[1] = fcM;
        gemm_mfma<<<dim3(D_ / 128, NTOK / 128, 2), 256, 0, stream>>>(gb, D2_, 0);
    }

    // 7) output projections -> fp32 d_out
    {
        GemmJob gb = {};
        gb.X[0] = fcP; gb.Wt[0] = WoT;  gb.bias[0] = bo;  gb.Y[0] = out;
        gb.X[1] = fcM; gb.Wt[1] = WomT; gb.bias[1] = bom; gb.Y[1] = out + ND_;
        gemm_mfma<<<dim3(D_ / 128, NTOK / 128, 2), 256, 0, stream>>>(gb, D_, 1);
    }
}